// Round 16
// baseline (257.736 us; speedup 1.0000x reference)
//
#include <hip/hip_runtime.h>

#define BINS 10
#define TPB  256
#define NBLK 2048

// ======================= per-element update (r15-exact) ======================
// Sign-bit integer masks, vcc-free bins:
//   d = ye - L;  nm = (int)bits(d)>>31   (-1 if ye<L, 0 if ye>=L)
//   S[b] += bits(bce) & ~nm              (adds +0.0f when lt: bit-identical)
//   Mneg[b] += nm;  cnt_ge[b] = nproc + Mneg[b]
// Invalid (w==0): ye=-60 -> lt all thresholds AND softplus(-60)==+0.0f exactly.
#define GHMC_ELEM(pk, tk, wk)                                                 \
    do {                                                                      \
        float tm_ = __builtin_fmaf((tk), -2.0f, 1.0f);                        \
        float y_  = tm_ * (pk);                                               \
        bool  v_  = ((wk) > 0.0f);                                            \
        float ye_ = v_ ? y_ : -60.0f;                                         \
        float e_  = __expf(-__builtin_fabsf(ye_));                            \
        float onep_ = 1.0f + e_;                                              \
        float bce_  = __builtin_fmaf(0.69314718055994530942f,                 \
                                     __log2f(onep_),                          \
                                     __builtin_fmaxf(ye_, 0.0f));             \
        unsigned bb_ = __float_as_uint(bce_);                                 \
        S[0]  += bce_;                                                        \
        c0f   += (wk);                                                        \
        nproc += 1;                                                           \
        _Pragma("unroll")                                                     \
        for (int b_ = 1; b_ < BINS; ++b_) {                                   \
            float d_ = ye_ - kL[b_ - 1];                                      \
            int  nm_ = ((int)__float_as_uint(d_)) >> 31;                      \
            Mneg[b_ - 1] += nm_;                                              \
            S[b_] += __uint_as_float(~(unsigned)nm_ & bb_);                   \
        }                                                                     \
    } while (0)

#define GHMC_ELEM4(P, T, W_)                                                  \
    do {                                                                      \
        GHMC_ELEM((P).x, (T).x, (W_).x);                                      \
        GHMC_ELEM((P).y, (T).y, (W_).y);                                      \
        GHMC_ELEM((P).z, (T).z, (W_).z);                                      \
        GHMC_ELEM((P).w, (T).w, (W_).w);                                      \
    } while (0)

#define GHMC_DECLS                                                            \
    const float kL[9] = { -2.1972246f, -1.3862944f, -0.84729786f,             \
                          -0.40546511f, 0.0f, 0.40546511f, 0.84729786f,       \
                          1.3862944f, 2.1972246f };                           \
    float S[BINS];                                                            \
    _Pragma("unroll") for (int b = 0; b < BINS; ++b) S[b] = 0.0f;             \
    int Mneg[BINS - 1];                                                       \
    _Pragma("unroll") for (int b = 0; b < BINS - 1; ++b) Mneg[b] = 0;         \
    float c0f = 0.0f;                                                         \
    int nproc = 0;

#define GHMC_BLOCKRED                                                         \
    float lsum[BINS];                                                         \
    int   lcnt[BINS];                                                         \
    {                                                                         \
        int Cc[BINS];                                                         \
        Cc[0] = (int)c0f;                                                     \
        _Pragma("unroll")                                                     \
        for (int b = 1; b < BINS; ++b) Cc[b] = nproc + Mneg[b - 1];           \
        _Pragma("unroll")                                                     \
        for (int b = 0; b < BINS - 1; ++b) {                                  \
            lsum[b] = S[b] - S[b + 1];                                        \
            lcnt[b] = Cc[b] - Cc[b + 1];                                      \
        }                                                                     \
        lsum[BINS - 1] = S[BINS - 1];                                         \
        lcnt[BINS - 1] = Cc[BINS - 1];                                        \
    }                                                                         \
    __shared__ float s_bsum[BINS];                                            \
    __shared__ int   s_bcnt[BINS];                                            \
    if (threadIdx.x < BINS) { s_bsum[threadIdx.x] = 0.0f;                     \
                              s_bcnt[threadIdx.x] = 0; }                      \
    __syncthreads();                                                          \
    {                                                                         \
        const int lane = threadIdx.x & 63;                                    \
        _Pragma("unroll")                                                     \
        for (int b = 0; b < BINS; ++b) {                                      \
            float s = lsum[b];                                                \
            int   c = lcnt[b];                                                \
            _Pragma("unroll")                                                 \
            for (int off = 32; off > 0; off >>= 1) {                          \
                s += __shfl_xor(s, off, 64);                                  \
                c += __shfl_xor(c, off, 64);                                  \
            }                                                                 \
            if (lane == 0 && c != 0) {                                        \
                atomicAdd(&s_bsum[b], s);                                     \
                atomicAdd(&s_bcnt[b], c);                                     \
            }                                                                 \
        }                                                                     \
    }                                                                         \
    __syncthreads();

// ======================= main: relaxed register budget =======================
// r15 anomaly: VGPR_Count=32 vs ~65 live registers -> allocator is spilling to
// scratch (L2-resident, invisible in WRITE_SIZE, VMEM-stall not VALU) and/or
// sinking the prefetch (r8 behavior). __launch_bounds__(256,2) RELAXES the
// budget to ~128 VGPR (r5 tested the constraining direction and spilled; the
// relaxing direction was never tested). Depth-2 prefetch restored: ~1000 cyc of
// own-compute between load issue and use -> latency hidden even at 2 waves/EU.
__global__ __launch_bounds__(256, 2) void ghmc_main(
    const float* __restrict__ pred, const float* __restrict__ targ,
    const float* __restrict__ lw,
    float* __restrict__ slot_sum, int* __restrict__ slot_cnt, int n) {

    GHMC_DECLS

    const int nvec  = n >> 2;
    const int start = (int)(((long long)nvec * blockIdx.x) / gridDim.x);
    const int end   = (int)(((long long)nvec * (blockIdx.x + 1)) / gridDim.x);

    const float4* p4 = (const float4*)pred;
    const float4* t4 = (const float4*)targ;
    const float4* w4 = (const float4*)lw;

    // depth-2 register pipeline
    const int i0 = start + (int)threadIdx.x;
    const int i1 = i0 + TPB;
    float4 p0, t0, w0, p1, t1, w1;
    const bool h0 = (i0 < end);
    const bool h1 = (i1 < end);
    if (h0) { p0 = p4[i0]; t0 = t4[i0]; w0 = w4[i0]; }
    if (h1) { p1 = p4[i1]; t1 = t4[i1]; w1 = w4[i1]; }

    for (int j = i0 + 2 * TPB; j < end; j += TPB) {
        float4 pn = p4[j], tn = t4[j], wn = w4[j];
        GHMC_ELEM4(p0, t0, w0);
        p0 = p1; t0 = t1; w0 = w1;
        p1 = pn; t1 = tn; w1 = wn;
    }
    if (h0) GHMC_ELEM4(p0, t0, w0);
    if (h1) GHMC_ELEM4(p1, t1, w1);

    // scalar tail (n not divisible by 4)
    {
        int rem  = n & 3;
        int gtid = blockIdx.x * TPB + (int)threadIdx.x;
        if (gtid < rem) {
            int idx = (nvec << 2) + gtid;
            float pk = pred[idx], tk = targ[idx], wk = lw[idx];
            GHMC_ELEM(pk, tk, wk);
        }
    }

    GHMC_BLOCKRED

    // plain stores to private slots (always overwritten -> poison-safe; no
    // zero kernel, no global atomics, no fence -- r12 verdict on the tail)
    if (threadIdx.x < BINS) {
        slot_sum[threadIdx.x * gridDim.x + blockIdx.x] = s_bsum[threadIdx.x];
        slot_cnt[threadIdx.x * gridDim.x + blockIdx.x] = s_bcnt[threadIdx.x];
    }
}

// ======================= finalize: reduce 2048 slots =========================
__global__ __launch_bounds__(256) void ghmc_finalize(
    const float* __restrict__ slot_sum, const int* __restrict__ slot_cnt,
    float* __restrict__ out, int nblk) {
    float ps[BINS];
    int   pc[BINS];
#pragma unroll
    for (int b = 0; b < BINS; ++b) { ps[b] = 0.0f; pc[b] = 0; }
    for (int i = (int)threadIdx.x; i < nblk; i += TPB) {
#pragma unroll
        for (int b = 0; b < BINS; ++b) {
            ps[b] += slot_sum[b * nblk + i];
            pc[b] += slot_cnt[b * nblk + i];
        }
    }
    __shared__ float s_s[BINS];
    __shared__ int   s_c[BINS];
    if (threadIdx.x < BINS) { s_s[threadIdx.x] = 0.0f; s_c[threadIdx.x] = 0; }
    __syncthreads();
    const int lane = threadIdx.x & 63;
#pragma unroll
    for (int b = 0; b < BINS; ++b) {
        float s = ps[b];
        int   c = pc[b];
#pragma unroll
        for (int off = 32; off > 0; off >>= 1) {
            s += __shfl_xor(s, off, 64);
            c += __shfl_xor(c, off, 64);
        }
        if (lane == 0) { atomicAdd(&s_s[b], s); atomicAdd(&s_c[b], c); }
    }
    __syncthreads();
    if (threadIdx.x == 0) {
        float acc = 0.0f;
        int nb = 0;
        for (int b = 0; b < BINS; ++b) {
            int c = s_c[b];
            if (c > 0) { nb += 1; acc += s_s[b] / (float)c; }
        }
        out[0] = (nb > 0) ? (acc / (float)nb) : 0.0f;  // LOSS_WEIGHT = 1
    }
}

extern "C" void kernel_launch(void* const* d_in, const int* in_sizes, int n_in,
                              void* d_out, int out_size, void* d_ws, size_t ws_size,
                              hipStream_t stream) {
    const float* pred = (const float*)d_in[0];
    const float* targ = (const float*)d_in[1];
    const float* lw   = (const float*)d_in[2];
    float* out = (float*)d_out;
    const int n = in_sizes[0];   // 262144*80 = 20,971,520

    // ws: [0, 81920) slot_sum (2048 x 10 x 4B); [81920, 163840) slot_cnt
    float* slot_sum = (float*)d_ws;
    int*   slot_cnt = (int*)((char*)d_ws + 81920);

    ghmc_main<<<NBLK, TPB, 0, stream>>>(pred, targ, lw, slot_sum, slot_cnt, n);
    ghmc_finalize<<<1, TPB, 0, stream>>>(slot_sum, slot_cnt, out, NBLK);
}